// Round 9
// baseline (230.672 us; speedup 1.0000x reference)
//
#include <hip/hip_runtime.h>
#include <hip/hip_bf16.h>

#define NEG_SLOPE 0.2f
#define NBUCK 782      // ceil(100000 / 128) buckets of 128 dst nodes
#define ABLK 8192      // edges per bucket_edges block (r4 champion config)
#define CAP 3072       // max edges per bucket (mean 2048, sd ~45 -> +22 sigma)

typedef __attribute__((ext_vector_type(8))) short bf16x8v;
typedef __attribute__((ext_vector_type(4))) float f32x4;

__device__ __forceinline__ unsigned f2bf_bits(float f) {
    unsigned u = __float_as_uint(f);
    return (u + 0x7fffu + ((u >> 16) & 1u)) >> 16;   // RNE fp32 -> bf16 bits
}
__device__ __forceinline__ float bflo(unsigned u) { return __uint_as_float(u << 16); }
__device__ __forceinline__ float bfhi(unsigned u) { return __uint_as_float(u & 0xffff0000u); }

// ---------------------------------------------------------------------------
// MFMA GEMM: [h | as | ad] = bf16(x) @ B[128,144], fp32 acc. (r4 verbatim)
// Block: 256 thr = 4 waves, 64 rows. Wave: 16 rows x 144 cols = 9 MFMA tiles.
// ---------------------------------------------------------------------------
__global__ __launch_bounds__(256) void gemm_mfma(const float* __restrict__ x,
                                                 const short* __restrict__ WtE,
                                                 short* __restrict__ hout,
                                                 float* __restrict__ as,
                                                 float* __restrict__ ad, int N) {
    __shared__ short xs[64 * 136];
    __shared__ short wt[144 * 136];
    const int tid = threadIdx.x;
    const int r0 = blockIdx.x * 64;

#pragma unroll
    for (int p = 0; p < 9; ++p) {
        int idx = p * 256 + tid;           // 2304 chunks of 8 shorts
        int n = idx >> 4, kk = (idx & 15) * 8;
        *(uint4*)&wt[n * 136 + kk] = *(const uint4*)(WtE + n * 128 + kk);
    }
#pragma unroll
    for (int p = 0; p < 8; ++p) {
        int lin = p * 1024 + tid * 4;
        int row = lin >> 7, k = lin & 127;
        int gr = r0 + row;
        int grc = gr < N ? gr : N - 1;
        float4 v = *(const float4*)(x + (size_t)grc * 128 + k);
        unsigned p0 = f2bf_bits(v.x) | (f2bf_bits(v.y) << 16);
        unsigned p1 = f2bf_bits(v.z) | (f2bf_bits(v.w) << 16);
        *(uint2*)&xs[row * 136 + k] = make_uint2(p0, p1);
    }
    __syncthreads();

    const int wv = tid >> 6;
    const int lane = tid & 63;
    const int lc = lane & 15, quad = lane >> 4;
    f32x4 acc[9];
#pragma unroll
    for (int c = 0; c < 9; ++c) acc[c] = (f32x4){0.f, 0.f, 0.f, 0.f};
    const short* aB = &xs[(wv * 16 + lc) * 136 + quad * 8];
    const short* bB = &wt[lc * 136 + quad * 8];
#pragma unroll
    for (int kc = 0; kc < 4; ++kc) {
        bf16x8v af = *(const bf16x8v*)(aB + kc * 32);
#pragma unroll
        for (int c = 0; c < 9; ++c) {
            bf16x8v bf = *(const bf16x8v*)(bB + c * (16 * 136) + kc * 32);
            acc[c] = __builtin_amdgcn_mfma_f32_16x16x32_bf16(af, bf, acc[c], 0, 0, 0);
        }
    }

    const int rowb = r0 + wv * 16 + quad * 4;
#pragma unroll
    for (int c = 0; c < 8; ++c) {
#pragma unroll
        for (int r = 0; r < 4; ++r) {
            int row = rowb + r;
            if (row < N) hout[(size_t)row * 128 + c * 16 + lc] = (short)f2bf_bits(acc[c][r]);
        }
    }
    // alpha columns: lc<8 -> as head lc; lc>=8 -> ad head lc-8
#pragma unroll
    for (int r = 0; r < 4; ++r) {
        int row = rowb + r;
        if (row < N) {
            if (lc < 8) as[row * 8 + lc] = acc[8][r];
            else        ad[row * 8 + (lc - 8)] = acc[8][r];
        }
    }
}

// ---------------------------------------------------------------------------
// Phase A: bucket edges by dst>>7 into per-block slabs. (r4 verbatim)
// Blocks [0,nblk): bucketing (8192 edges). Blocks [nblk,nblk+18): prep_w.
// ---------------------------------------------------------------------------
__global__ __launch_bounds__(1024) void bucket_edges(const int* __restrict__ ei, int E,
                                                     int nblk,
                                                     unsigned* __restrict__ slab,
                                                     int2* __restrict__ csG,
                                                     const float* __restrict__ W,
                                                     const float* __restrict__ a_src,
                                                     const float* __restrict__ a_dst,
                                                     short* __restrict__ WtE) {
    const int t = threadIdx.x;
    const int blk = blockIdx.x;

    if (blk >= nblk) {            // ---- prep_w path: 18 blocks x 1024 = 18432
        int id = (blk - nblk) * 1024 + t;
        if (id < 144 * 128) {
            int n = id >> 7, k = id & 127;
            float v;
            if (n < 128) {
                v = W[k * 128 + n];
            } else if (n < 136) {
                int hh = n - 128; float s = 0.f;
#pragma unroll
                for (int d = 0; d < 16; ++d) s += W[k * 128 + hh * 16 + d] * a_src[hh * 16 + d];
                v = s;
            } else {
                int hh = n - 136; float s = 0.f;
#pragma unroll
                for (int d = 0; d < 16; ++d) s += W[k * 128 + hh * 16 + d] * a_dst[hh * 16 + d];
                v = s;
            }
            WtE[id] = (short)f2bf_bits(v);
        }
        return;
    }

    __shared__ int hist[1024];
    __shared__ int cur[NBUCK];
    __shared__ int wpart[16];
    const int base = blk * ABLK;
    int count = E - base; if (count > ABLK) count = ABLK;

    int sr[8], dr[8];
    hist[t] = 0;
#pragma unroll
    for (int k = 0; k < 8; ++k) {
        int i = k * 1024 + t;
        if (i < count) { sr[k] = ei[base + i]; dr[k] = ei[E + base + i]; }
    }
    __syncthreads();
#pragma unroll
    for (int k = 0; k < 8; ++k) {
        int i = k * 1024 + t;
        if (i < count) atomicAdd(&hist[dr[k] >> 7], 1);
    }
    __syncthreads();
    int v = hist[t];
    int lane = t & 63, wid = t >> 6;
    int sc = v;
#pragma unroll
    for (int off = 1; off < 64; off <<= 1) { int u = __shfl_up(sc, off); if (lane >= off) sc += u; }
    if (lane == 63) wpart[wid] = sc;
    __syncthreads();
    if (wid == 0 && lane < 16) {
        int wv = wpart[lane], wsum = wv;
#pragma unroll
        for (int off = 1; off < 16; off <<= 1) { int u = __shfl_up(wsum, off); if (lane >= off) wsum += u; }
        wpart[lane] = wsum - wv;
    }
    __syncthreads();
    int excl = sc - v + wpart[wid];
    if (t < NBUCK) {
        csG[(size_t)blk * NBUCK + t] = make_int2(v, excl);
        cur[t] = excl;
    }
    __syncthreads();
#pragma unroll
    for (int k = 0; k < 8; ++k) {
        int i = k * 1024 + t;
        if (i < count) {
            int d = dr[k];
            int pos = atomicAdd(&cur[d >> 7], 1);
            slab[(size_t)blk * ABLK + pos] = (unsigned)sr[k] | ((unsigned)(d & 127) << 17);
        }
    }
}

// ---------------------------------------------------------------------------
// Fused CSR+aggregate: one block (512 thr = 8 waves) per bucket of 128 nodes.
// Phase 1 (r4 build_csr verbatim, but CSR lands in LDS): segment gather into
//   eL, hist+scan -> per-node start/count (lpS/lpC), scatter into sEL (LDS).
//   Deletes the build_csr dispatch + the sortedSrc/rowS/rowE global
//   round-trip (~14 MB).
// Phase 2 (aggregate v5 logic, measured best): wave w handles nodes w, w+8,
//   ..., w+120 serially. Lane = channel-pair (head p = lane>>3); per edge
//   each lane loads one dword of the h row (coalesced 256B/edge) and FMAs
//   into a private f32x2; dsum per-lane -> zero cross-lane reduction. Edge
//   indices 8/round from LDS sEL + readlane -> SGPR addressing; indices +
//   as prefetched a round ahead. Numerics = v5 per node.
// LDS ~33 KB, VGPR ~40 -> launch_bounds(512,8): 32 waves/CU (> v5's 24).
// ---------------------------------------------------------------------------
__global__ __launch_bounds__(512, 8) void csr_aggregate(const unsigned* __restrict__ slab,
                                                        const int2* __restrict__ csG,
                                                        int nblk, int N,
                                                        const short* __restrict__ h,
                                                        const float* __restrict__ as,
                                                        const float* __restrict__ ad,
                                                        const float* __restrict__ bias,
                                                        float* __restrict__ out) {
    __shared__ int eL[CAP];
    __shared__ int sEL[CAP];
    __shared__ int incl[512];
    __shared__ int cS[512];
    __shared__ int stS[512];
    __shared__ int lp[128];
    __shared__ int lpS[128];
    __shared__ int lpC[128];
    __shared__ int wpart[8];
    __shared__ int halfSum;
    const int bb = blockIdx.x;
    const int t = threadIdx.x;
    const int nodeBase = bb << 7;
    const int lane = t & 63, wid = t >> 6;

    // ---------------- Phase 1: build bucket CSR in LDS ----------------
    int c = 0, st = 0;
    if (t < nblk) { int2 cs = csG[(size_t)t * NBUCK + bb]; c = cs.x; st = cs.y; }
    cS[t] = c; stS[t] = st;
    if (t < 128) lp[t] = 0;
    int sc = c;
#pragma unroll
    for (int off = 1; off < 64; off <<= 1) { int u = __shfl_up(sc, off); if (lane >= off) sc += u; }
    if (lane == 63) wpart[wid] = sc;
    __syncthreads();
    if (wid == 0 && lane < 8) {
        int wv = wpart[lane], wsum = wv;
#pragma unroll
        for (int off = 1; off < 8; off <<= 1) { int u = __shfl_up(wsum, off); if (lane >= off) wsum += u; }
        wpart[lane] = wsum - wv;
    }
    __syncthreads();
    incl[t] = sc + wpart[wid];
    __syncthreads();
    int total = incl[511];
    if (total > CAP) total = CAP;   // statically impossible; guards LDS OOB
    // 8-lane-group-per-segment gather: group g handles segments g, g+64, ...
    {
        const int grp = t >> 3, li = t & 7;
        for (int s = grp; s < nblk; s += 64) {
            int cc = cS[s];
            int off0 = incl[s] - cc;
            const unsigned* p = slab + (size_t)s * ABLK + stS[s];
            for (int i = li; i < cc; i += 8) eL[off0 + i] = (int)p[i];
        }
    }
    __syncthreads();
    for (int e = t; e < total; e += 512) atomicAdd(&lp[((unsigned)eL[e]) >> 17], 1);
    __syncthreads();
    // scan 128 node counts
    int cnt = 0, s2 = 0;
    if (t < 128) {
        cnt = lp[t];
        s2 = cnt;
#pragma unroll
        for (int off = 1; off < 64; off <<= 1) { int u = __shfl_up(s2, off); if (lane >= off) s2 += u; }
        if (t == 63) halfSum = s2;
    }
    __syncthreads();
    if (t < 128) {
        int inc2 = s2 + (t >= 64 ? halfSum : 0);
        int ex = inc2 - cnt;
        lpS[t] = ex;
        lpC[t] = cnt;
        lp[t] = ex;
    }
    __syncthreads();
    for (int e = t; e < total; e += 512) {
        unsigned pk = (unsigned)eL[e];
        int pos = atomicAdd(&lp[pk >> 17], 1);
        sEL[pos] = (int)(pk & 0x1FFFFu);
    }
    __syncthreads();

    // ---------------- Phase 2: aggregate (v5 logic), 16 nodes per wave ----
    const int p = lane >> 3;                 // head of this lane's channels
    const int q7 = lane & 7;
    for (int nl = wid; nl < 128; nl += 8) {
        const int node = nodeBase + nl;      // wave-uniform
        if (node >= N) continue;
        const int start = __builtin_amdgcn_readfirstlane(lpS[nl]);
        const int end   = start + __builtin_amdgcn_readfirstlane(lpC[nl]);
        const float adv = ad[node * 8 + p];

        float accx = 0.f, accy = 0.f, dsum = 0.f;

        int e = start;
        int iv = node;                        // safe default index
        { int q = e + q7; if (q < end) iv = sEL[q]; }

        while (e < end) {
            float asv[8]; unsigned hwv[8];
#pragma unroll
            for (int k = 0; k < 8; ++k) {
                int j = __builtin_amdgcn_readlane(iv, k);     // SGPR edge src
                asv[k] = as[j * 8 + p];
                hwv[k] = *(const unsigned*)(h + (size_t)j * 128 + lane * 2);
            }
            int en = e + 8;
            int iv2 = node;
            { int q = en + q7; if (q < end) iv2 = sEL[q]; }
#pragma unroll
            for (int k = 0; k < 8; ++k) {
                if (e + k < end) {            // scalar branch (e,end uniform)
                    float tt = asv[k] + adv;
                    tt = tt > 0.f ? tt : NEG_SLOPE * tt;
                    float w = __expf(tt);
                    unsigned u = hwv[k];
                    accx += w * bflo(u);
                    accy += w * bfhi(u);
                    dsum += w;
                }
            }
            iv = iv2; e = en;
        }

        // self-loop
        {
            float tt = as[node * 8 + p] + adv;
            tt = tt > 0.f ? tt : NEG_SLOPE * tt;
            float w = __expf(tt);
            unsigned u = *(const unsigned*)(h + (size_t)node * 128 + lane * 2);
            accx += w * bflo(u);
            accy += w * bfhi(u);
            dsum += w;
        }

        float inv = 1.0f / (dsum + 1e-16f);
        float2 bv = *(const float2*)(bias + lane * 2);
        float o0 = accx * inv + bv.x;
        float o1 = accy * inv + bv.y;
        o0 = o0 > 0.f ? o0 : 0.f;
        o1 = o1 > 0.f ? o1 : 0.f;
        *(float2*)(out + (size_t)node * 128 + lane * 2) = make_float2(o0, o1);
    }
}

extern "C" void kernel_launch(void* const* d_in, const int* in_sizes, int n_in,
                              void* d_out, int out_size, void* d_ws, size_t ws_size,
                              hipStream_t stream) {
    const float* x     = (const float*)d_in[0];
    const int*   ei    = (const int*)d_in[1];
    const float* W     = (const float*)d_in[2];
    const float* a_src = (const float*)d_in[3];
    const float* a_dst = (const float*)d_in[4];
    const float* bias  = (const float*)d_in[5];
    float* out = (float*)d_out;

    const int N = in_sizes[0] / 128;   // 100000
    const int E = in_sizes[1] / 2;     // 1600000
    const int nblk = (E + ABLK - 1) / ABLK;  // 196

    char* ws = (char*)d_ws;
    size_t off = 0;
    auto alloc = [&](size_t bytes) { void* p = ws + off; off = (off + bytes + 255) & ~(size_t)255; return p; };
    short*    h         = (short*)alloc((size_t)N * 128 * 2);
    float*    as        = (float*)alloc((size_t)N * 8 * 4);
    float*    ad        = (float*)alloc((size_t)N * 8 * 4);
    unsigned* slab      = (unsigned*)alloc((size_t)nblk * ABLK * 4);
    int2*     csG       = (int2*)alloc((size_t)nblk * NBUCK * 8);
    short*    WtE       = (short*)alloc((size_t)144 * 128 * 2);

    bucket_edges<<<nblk + 18, 1024, 0, stream>>>(ei, E, nblk, slab, csG, W, a_src, a_dst, WtE);
    gemm_mfma<<<(N + 63) / 64, 256, 0, stream>>>(x, WtE, h, as, ad, N);
    csr_aggregate<<<NBUCK, 512, 0, stream>>>(slab, csG, nblk, N, h, as, ad, bias, out);
}

// Round 10
// 223.726 us; speedup vs baseline: 1.0310x; 1.0310x over previous
//
#include <hip/hip_runtime.h>
#include <hip/hip_bf16.h>

#define NEG_SLOPE 0.2f
#define NBUCK 782      // ceil(100000 / 128) buckets of 128 dst nodes
#define ABLK 8192      // edges per bucket_edges block
#define CAP 3072       // max edges per bucket (mean 2048, sd ~45 -> +22 sigma)

typedef __attribute__((ext_vector_type(8))) short bf16x8v;
typedef __attribute__((ext_vector_type(4))) float f32x4;

__device__ __forceinline__ unsigned f2bf_bits(float f) {
    unsigned u = __float_as_uint(f);
    return (u + 0x7fffu + ((u >> 16) & 1u)) >> 16;   // RNE fp32 -> bf16 bits
}
__device__ __forceinline__ float bflo(unsigned u) { return __uint_as_float(u << 16); }
__device__ __forceinline__ float bfhi(unsigned u) { return __uint_as_float(u & 0xffff0000u); }

// ---------------------------------------------------------------------------
// MFMA GEMM: [h | as | ad] = bf16(x) @ B[128,144], fp32 acc.
// Block: 256 thr = 4 waves, 64 rows. Wave: 16 rows x 144 cols = 9 MFMA tiles.
// ---------------------------------------------------------------------------
__global__ __launch_bounds__(256) void gemm_mfma(const float* __restrict__ x,
                                                 const short* __restrict__ WtE,
                                                 short* __restrict__ hout,
                                                 float* __restrict__ as,
                                                 float* __restrict__ ad, int N) {
    __shared__ short xs[64 * 136];
    __shared__ short wt[144 * 136];
    const int tid = threadIdx.x;
    const int r0 = blockIdx.x * 64;

#pragma unroll
    for (int p = 0; p < 9; ++p) {
        int idx = p * 256 + tid;           // 2304 chunks of 8 shorts
        int n = idx >> 4, kk = (idx & 15) * 8;
        *(uint4*)&wt[n * 136 + kk] = *(const uint4*)(WtE + n * 128 + kk);
    }
#pragma unroll
    for (int p = 0; p < 8; ++p) {
        int lin = p * 1024 + tid * 4;
        int row = lin >> 7, k = lin & 127;
        int gr = r0 + row;
        int grc = gr < N ? gr : N - 1;
        float4 v = *(const float4*)(x + (size_t)grc * 128 + k);
        unsigned p0 = f2bf_bits(v.x) | (f2bf_bits(v.y) << 16);
        unsigned p1 = f2bf_bits(v.z) | (f2bf_bits(v.w) << 16);
        *(uint2*)&xs[row * 136 + k] = make_uint2(p0, p1);
    }
    __syncthreads();

    const int wv = tid >> 6;
    const int lane = tid & 63;
    const int lc = lane & 15, quad = lane >> 4;
    f32x4 acc[9];
#pragma unroll
    for (int c = 0; c < 9; ++c) acc[c] = (f32x4){0.f, 0.f, 0.f, 0.f};
    const short* aB = &xs[(wv * 16 + lc) * 136 + quad * 8];
    const short* bB = &wt[lc * 136 + quad * 8];
#pragma unroll
    for (int kc = 0; kc < 4; ++kc) {
        bf16x8v af = *(const bf16x8v*)(aB + kc * 32);
#pragma unroll
        for (int c = 0; c < 9; ++c) {
            bf16x8v bf = *(const bf16x8v*)(bB + c * (16 * 136) + kc * 32);
            acc[c] = __builtin_amdgcn_mfma_f32_16x16x32_bf16(af, bf, acc[c], 0, 0, 0);
        }
    }

    const int rowb = r0 + wv * 16 + quad * 4;
#pragma unroll
    for (int c = 0; c < 8; ++c) {
#pragma unroll
        for (int r = 0; r < 4; ++r) {
            int row = rowb + r;
            if (row < N) hout[(size_t)row * 128 + c * 16 + lc] = (short)f2bf_bits(acc[c][r]);
        }
    }
    // alpha columns: lc<8 -> as head lc; lc>=8 -> ad head lc-8
#pragma unroll
    for (int r = 0; r < 4; ++r) {
        int row = rowb + r;
        if (row < N) {
            if (lc < 8) as[row * 8 + lc] = acc[8][r];
            else        ad[row * 8 + (lc - 8)] = acc[8][r];
        }
    }
}

// ---------------------------------------------------------------------------
// Phase A: bucket edges by dst>>7 into per-block slabs. Register staging,
// packed uint32 = src | (dst&127)<<17. Hierarchical shfl scan.
// Blocks [0,nblk): bucketing. Blocks [nblk, nblk+18): absorbed prep_w work.
// ---------------------------------------------------------------------------
__global__ __launch_bounds__(1024) void bucket_edges(const int* __restrict__ ei, int E,
                                                     int nblk,
                                                     unsigned* __restrict__ slab,
                                                     int2* __restrict__ csG,
                                                     const float* __restrict__ W,
                                                     const float* __restrict__ a_src,
                                                     const float* __restrict__ a_dst,
                                                     short* __restrict__ WtE) {
    const int t = threadIdx.x;
    const int blk = blockIdx.x;

    if (blk >= nblk) {            // ---- prep_w path: 18 blocks x 1024 = 18432
        int id = (blk - nblk) * 1024 + t;
        if (id < 144 * 128) {
            int n = id >> 7, k = id & 127;
            float v;
            if (n < 128) {
                v = W[k * 128 + n];
            } else if (n < 136) {
                int hh = n - 128; float s = 0.f;
#pragma unroll
                for (int d = 0; d < 16; ++d) s += W[k * 128 + hh * 16 + d] * a_src[hh * 16 + d];
                v = s;
            } else {
                int hh = n - 136; float s = 0.f;
#pragma unroll
                for (int d = 0; d < 16; ++d) s += W[k * 128 + hh * 16 + d] * a_dst[hh * 16 + d];
                v = s;
            }
            WtE[id] = (short)f2bf_bits(v);
        }
        return;
    }

    __shared__ int hist[1024];
    __shared__ int cur[NBUCK];
    __shared__ int wpart[16];
    const int base = blk * ABLK;
    int count = E - base; if (count > ABLK) count = ABLK;

    int sr[8], dr[8];
    hist[t] = 0;
#pragma unroll
    for (int k = 0; k < 8; ++k) {
        int i = k * 1024 + t;
        if (i < count) { sr[k] = ei[base + i]; dr[k] = ei[E + base + i]; }
    }
    __syncthreads();
#pragma unroll
    for (int k = 0; k < 8; ++k) {
        int i = k * 1024 + t;
        if (i < count) atomicAdd(&hist[dr[k] >> 7], 1);
    }
    __syncthreads();
    int v = hist[t];
    int lane = t & 63, wid = t >> 6;
    int sc = v;
#pragma unroll
    for (int off = 1; off < 64; off <<= 1) { int u = __shfl_up(sc, off); if (lane >= off) sc += u; }
    if (lane == 63) wpart[wid] = sc;
    __syncthreads();
    if (wid == 0 && lane < 16) {
        int wv = wpart[lane], wsum = wv;
#pragma unroll
        for (int off = 1; off < 16; off <<= 1) { int u = __shfl_up(wsum, off); if (lane >= off) wsum += u; }
        wpart[lane] = wsum - wv;
    }
    __syncthreads();
    int excl = sc - v + wpart[wid];
    if (t < NBUCK) {
        csG[(size_t)blk * NBUCK + t] = make_int2(v, excl);
        cur[t] = excl;
    }
    __syncthreads();
#pragma unroll
    for (int k = 0; k < 8; ++k) {
        int i = k * 1024 + t;
        if (i < count) {
            int d = dr[k];
            int pos = atomicAdd(&cur[d >> 7], 1);
            slab[(size_t)blk * ABLK + pos] = (unsigned)sr[k] | ((unsigned)(d & 127) << 17);
        }
    }
}

// ---------------------------------------------------------------------------
// Phase B: per bucket of 128 dst nodes. 8-lane-group-per-segment LDS gather,
// hist + scan -> rowS/rowE (fixed CAP region per bucket), scatter sortedSrc.
// ---------------------------------------------------------------------------
__global__ __launch_bounds__(512) void build_csr(const unsigned* __restrict__ slab,
                                                 const int2* __restrict__ csG,
                                                 int nblk, int N,
                                                 int* __restrict__ rowS,
                                                 int* __restrict__ rowE,
                                                 int* __restrict__ sortedSrc) {
    __shared__ int eL[CAP];
    __shared__ int incl[512];
    __shared__ int cS[512];
    __shared__ int stS[512];
    __shared__ int lp[128];
    __shared__ int wpart[8];
    __shared__ int halfSum;
    const int bb = blockIdx.x;
    const int t = threadIdx.x;
    const int nodeBase = bb << 7;
    const int bBase = bb * CAP;

    int c = 0, st = 0;
    if (t < nblk) { int2 cs = csG[(size_t)t * NBUCK + bb]; c = cs.x; st = cs.y; }
    cS[t] = c; stS[t] = st;
    if (t < 128) lp[t] = 0;
    int lane = t & 63, wid = t >> 6;
    int sc = c;
#pragma unroll
    for (int off = 1; off < 64; off <<= 1) { int u = __shfl_up(sc, off); if (lane >= off) sc += u; }
    if (lane == 63) wpart[wid] = sc;
    __syncthreads();
    if (wid == 0 && lane < 8) {
        int wv = wpart[lane], wsum = wv;
#pragma unroll
        for (int off = 1; off < 8; off <<= 1) { int u = __shfl_up(wsum, off); if (lane >= off) wsum += u; }
        wpart[lane] = wsum - wv;
    }
    __syncthreads();
    incl[t] = sc + wpart[wid];
    __syncthreads();
    int total = incl[511];
    if (total > CAP) total = CAP;   // statically impossible; guards LDS OOB
    // 8-lane-group-per-segment gather: group g handles segments g, g+64, ...
    {
        const int grp = t >> 3, li = t & 7;
        for (int s = grp; s < nblk; s += 64) {
            int cc = cS[s];
            int off0 = incl[s] - cc;
            const unsigned* p = slab + (size_t)s * ABLK + stS[s];
            for (int i = li; i < cc; i += 8) eL[off0 + i] = (int)p[i];
        }
    }
    __syncthreads();
    for (int e = t; e < total; e += 512) atomicAdd(&lp[((unsigned)eL[e]) >> 17], 1);
    __syncthreads();
    // scan 128 node counts
    int cnt = 0, s2 = 0;
    if (t < 128) {
        cnt = lp[t];
        s2 = cnt;
#pragma unroll
        for (int off = 1; off < 64; off <<= 1) { int u = __shfl_up(s2, off); if (lane >= off) s2 += u; }
        if (t == 63) halfSum = s2;
    }
    __syncthreads();
    if (t < 128) {
        int inc2 = s2 + (t >= 64 ? halfSum : 0);
        int ex = inc2 - cnt;
        int gn = nodeBase + t;
        if (gn < N) { rowS[gn] = bBase + ex; rowE[gn] = bBase + ex + cnt; }
        lp[t] = ex;
    }
    __syncthreads();
    for (int e = t; e < total; e += 512) {
        unsigned pk = (unsigned)eL[e];
        int pos = atomicAdd(&lp[pk >> 17], 1);
        sortedSrc[bBase + pos] = (int)(pk & 0x1FFFFu);
    }
}

// ---------------------------------------------------------------------------
// Aggregate v5 (measured best 81.3us): one wave per dst node; lane =
// channel-pair. Lane l owns output channels 2l,2l+1 (head = l>>3). Per edge:
// each lane loads one dword of the h row (coalesced 256B/edge) and FMAs into
// a private f32x2; dsum per-lane -> ZERO cross-lane reduction, zero DS ops.
// Edge indices: 8/round via broadcast load + readlane -> SGPR addressing;
// round's 16 as/h loads issue back-to-back (indices prefetched a round
// ahead). r8 evidence: this kernel is bound by the random-256B gather path
// (~4 TB/s; FETCH pinned at 268 MB independent of VALU count) — structural
// floor of this layout.
// ---------------------------------------------------------------------------
__global__ __launch_bounds__(256, 8) void aggregate(const int* __restrict__ rowS,
                                                    const int* __restrict__ rowE,
                                                    const int* __restrict__ sortedSrc,
                                                    const short* __restrict__ h,
                                                    const float* __restrict__ as,
                                                    const float* __restrict__ ad,
                                                    const float* __restrict__ bias,
                                                    float* __restrict__ out, int N) {
    const int lane = threadIdx.x & 63;
    const int wv = threadIdx.x >> 6;
    const int node = __builtin_amdgcn_readfirstlane(blockIdx.x * 4 + wv);
    if (node >= N) return;
    const int p = lane >> 3;                 // head of this lane's channels
    const int start = __builtin_amdgcn_readfirstlane(rowS[node]);
    const int end   = __builtin_amdgcn_readfirstlane(rowE[node]);
    const float adv = ad[node * 8 + p];

    float accx = 0.f, accy = 0.f;
    float dsum = 0.f;

    int e = start;
    int iv = node;                            // safe default index
    { int q = e + (lane & 7); if (q < end) iv = sortedSrc[q]; }

    while (e < end) {
        float asv[8]; unsigned hwv[8];
#pragma unroll
        for (int k = 0; k < 8; ++k) {
            int j = __builtin_amdgcn_readlane(iv, k);     // SGPR edge src
            asv[k] = as[j * 8 + p];
            hwv[k] = *(const unsigned*)(h + (size_t)j * 128 + lane * 2);
        }
        int en = e + 8;
        int iv2 = node;
        { int q = en + (lane & 7); if (q < end) iv2 = sortedSrc[q]; }
#pragma unroll
        for (int k = 0; k < 8; ++k) {
            if (e + k < end) {                // scalar branch (e,end uniform)
                float tt = asv[k] + adv;
                tt = tt > 0.f ? tt : NEG_SLOPE * tt;
                float w = __expf(tt);
                unsigned u = hwv[k];
                accx += w * bflo(u);
                accy += w * bfhi(u);
                dsum += w;
            }
        }
        iv = iv2; e = en;
    }

    // self-loop
    {
        float tt = as[node * 8 + p] + adv;
        tt = tt > 0.f ? tt : NEG_SLOPE * tt;
        float w = __expf(tt);
        unsigned u = *(const unsigned*)(h + (size_t)node * 128 + lane * 2);
        accx += w * bflo(u);
        accy += w * bfhi(u);
        dsum += w;
    }

    float inv = 1.0f / (dsum + 1e-16f);
    float2 bv = *(const float2*)(bias + lane * 2);
    float o0 = accx * inv + bv.x;
    float o1 = accy * inv + bv.y;
    o0 = o0 > 0.f ? o0 : 0.f;
    o1 = o1 > 0.f ? o1 : 0.f;
    *(float2*)(out + (size_t)node * 128 + lane * 2) = make_float2(o0, o1);
}

extern "C" void kernel_launch(void* const* d_in, const int* in_sizes, int n_in,
                              void* d_out, int out_size, void* d_ws, size_t ws_size,
                              hipStream_t stream) {
    const float* x     = (const float*)d_in[0];
    const int*   ei    = (const int*)d_in[1];
    const float* W     = (const float*)d_in[2];
    const float* a_src = (const float*)d_in[3];
    const float* a_dst = (const float*)d_in[4];
    const float* bias  = (const float*)d_in[5];
    float* out = (float*)d_out;

    const int N = in_sizes[0] / 128;   // 100000
    const int E = in_sizes[1] / 2;     // 1600000
    const int nblk = (E + ABLK - 1) / ABLK;  // 196

    char* ws = (char*)d_ws;
    size_t off = 0;
    auto alloc = [&](size_t bytes) { void* p = ws + off; off = (off + bytes + 255) & ~(size_t)255; return p; };
    short*    h         = (short*)alloc((size_t)N * 128 * 2);
    float*    as        = (float*)alloc((size_t)N * 8 * 4);
    float*    ad        = (float*)alloc((size_t)N * 8 * 4);
    unsigned* slab      = (unsigned*)alloc((size_t)nblk * ABLK * 4);
    int2*     csG       = (int2*)alloc((size_t)nblk * NBUCK * 8);
    int*      sortedSrc = (int*)alloc((size_t)NBUCK * CAP * 4);
    int*      rowS      = (int*)alloc((size_t)N * 4);
    int*      rowE      = (int*)alloc((size_t)N * 4);
    short*    WtE       = (short*)alloc((size_t)144 * 128 * 2);

    bucket_edges<<<nblk + 18, 1024, 0, stream>>>(ei, E, nblk, slab, csG, W, a_src, a_dst, WtE);
    gemm_mfma<<<(N + 63) / 64, 256, 0, stream>>>(x, WtE, h, as, ad, N);
    build_csr<<<NBUCK, 512, 0, stream>>>(slab, csG, nblk, N, rowS, rowE, sortedSrc);
    aggregate<<<(N + 3) / 4, 256, 0, stream>>>(rowS, rowE, sortedSrc, h, as, ad, bias, out, N);
}